// Round 5
// baseline (439.216 us; speedup 1.0000x reference)
//
#include <hip/hip_runtime.h>
#include <math.h>

// Problem constants
#define BB     32
#define NBANDS 9
#define NCHAN  64
#define NTIME  4096
#define CC     288           // 32*9
#define TLEN   7
#define NSEG   8
#define SEGLEN 512           // NTIME/8
#define NCLASS 4

// ws layout (float-indexed). WS_WF region holds Wh+Wl as _Float16.
#define WS_WF    0                      // 288*64 floats (= Wh[18432]h + Wl[18432]h)
#define WS_BIAS  (WS_WF + CC*NCHAN)     // 288
#define WS_S1    (WS_BIAS + CC)         // 32*288*8
#define WS_S2    (WS_S1 + BB*CC*NSEG)   // 32*288*8
#define WS_FLAT  (WS_S2 + BB*CC*NSEG)   // 32*4032

typedef _Float16 f16;
typedef __attribute__((ext_vector_type(8))) _Float16 f16x8;
typedef __attribute__((ext_vector_type(4))) float floatx4;

// LDS tile geometry: phase = 64 t, 64 rows. 16 row-groups (I) of 4 rows.
// Each I-block: 256 floats of data, padded stride 260 floats (1040 B, 16B
// multiple) so B-frag quad offsets = 2*260 = 520 ≡ 8 (mod 32 banks)
// -> 2-way conflicts only (free, m136).
#define IBLK 260
#define BUFF (16 * IBLK)     // 4160 floats per buffer

__device__ __forceinline__ void gl_lds16(const float* g, float* l) {
  __builtin_amdgcn_global_load_lds(
      (const __attribute__((address_space(1))) void*)g,
      (__attribute__((address_space(3))) void*)l, 16, 0, 0);
}

// ---------------- K0: fold renorm(conv_w,2)+BN into split-fp16 W -----------
// Wh/Wl layout: [g][h][c_local]  (A-operand-friendly: c contiguous)
__global__ __launch_bounds__(64) void k0_fold(
    const float* __restrict__ cw, const float* __restrict__ cb,
    const float* __restrict__ gam, const float* __restrict__ bet,
    const float* __restrict__ mu, const float* __restrict__ var,
    f16* __restrict__ Wh, f16* __restrict__ Wl, float* __restrict__ biasf) {
  int c = blockIdx.x;              // 0..287 global channel
  int h = threadIdx.x;             // 0..63
  int g = c >> 5, cc = c & 31;
  float w = cw[c * NCHAN + h];
  float sq = w * w;
#pragma unroll
  for (int off = 32; off; off >>= 1) sq += __shfl_down(sq, off, 64);
  sq = __shfl(sq, 0, 64);
  float norm = sqrtf(sq);
  float scale = fminf(1.0f, 2.0f / fmaxf(norm, 1e-7f));
  float bns = gam[c] / sqrtf(var[c] + 1e-5f);
  float wf = w * scale * bns;
  f16 hi = (f16)wf;
  f16 lo = (f16)(wf - (float)hi);
  int o = g * (NCHAN * 32) + h * 32 + cc;
  Wh[o] = hi;
  Wl[o] = lo;
  if (h == 0) biasf[c] = (cb[c] - mu[c]) * bns + bet[c];
}

// ---------------- K1: LDS-pipelined split-fp16 MFMA conv + moments ---------
// Block = (b,g,seg): D[32c x 512t] = W[32x64] . X[64x512]. 8 phases of 64 t.
// Staging: global_load_lds dwordx4, 4 instrs/wave/phase, double-buffered.
// LDS layout: idx(h,t) = (h>>2)*IBLK + (h&3)*64 + (t>>2)*4 + (t&3).
// Compute: wave w owns n-tile cols t = w*16+li. Split-fp16 precision:
// Wh.Xh + Wh.Xl + Wl.Xh (fp32-grade; single-bf16 failed at absmax 7).
__global__ __launch_bounds__(256, 4) void k1_conv(
    const float* __restrict__ x, const f16* __restrict__ Wh,
    const f16* __restrict__ Wl, const float* __restrict__ biasf,
    float* __restrict__ S1, float* __restrict__ S2) {
  __shared__ float lds[2][BUFF];
  __shared__ float part[2][32][4];

  int gid = blockIdx.x;
  int seg = gid & 7;
  int g = (gid >> 3) % NBANDS;
  int b = gid / (NBANDS * NSEG);
  int tid = threadIdx.x;
  int w = tid >> 6, lane = tid & 63;
  int quad = lane >> 4, li = lane & 15;

  const float* xp = x + (size_t)(b * NBANDS + g) * NCHAN * NTIME + seg * SEGLEN;
  const f16* whp = Wh + g * (NCHAN * 32);
  const f16* wlp = Wl + g * (NCHAN * 32);

  // A fragments: ah/al[mt][kb] elem j -> W[c=mt*16+li][h=kb*32+quad*8+j]
  f16x8 ah[2][2], al[2][2];
#pragma unroll
  for (int mt = 0; mt < 2; ++mt)
#pragma unroll
    for (int kb = 0; kb < 2; ++kb)
#pragma unroll
      for (int j = 0; j < 8; ++j) {
        int idx = (kb * 32 + quad * 8 + j) * 32 + mt * 16 + li;
        ah[mt][kb][j] = whp[idx];
        al[mt][kb][j] = wlp[idx];
      }

  float biasr[2][4];
#pragma unroll
  for (int mt = 0; mt < 2; ++mt)
#pragma unroll
    for (int r = 0; r < 4; ++r)
      biasr[mt][r] = biasf[g * 32 + mt * 16 + quad * 4 + r];

  float s1a[2][4], s2a[2][4];
#pragma unroll
  for (int mt = 0; mt < 2; ++mt)
#pragma unroll
    for (int r = 0; r < 4; ++r) { s1a[mt][r] = 0.0f; s2a[mt][r] = 0.0f; }

  // ---- stage phase 0 into buf 0: wave w handles row-groups I = w*4+i ----
#pragma unroll
  for (int i = 0; i < 4; ++i) {
    int I = w * 4 + i;
    gl_lds16(xp + (size_t)(I * 4 + quad) * NTIME + li * 4, &lds[0][I * IBLK]);
  }

#pragma unroll 1
  for (int p = 0; p < 8; ++p) {
    int cur = p & 1;
    if (p < 7) {
#pragma unroll
      for (int i = 0; i < 4; ++i) {
        int I = w * 4 + i;
        gl_lds16(xp + (size_t)(I * 4 + quad) * NTIME + (p + 1) * 64 + li * 4,
                 &lds[cur ^ 1][I * IBLK]);
      }
      asm volatile("s_waitcnt vmcnt(4)" ::: "memory");  // phase-p loads done
    } else {
      asm volatile("s_waitcnt vmcnt(0)" ::: "memory");
    }
    __syncthreads();

    // compute: this wave's 16-col tile (cols t = w*16 + li within phase)
    const float* Lb = lds[cur];
    floatx4 acc0 = {0.0f, 0.0f, 0.0f, 0.0f};
    floatx4 acc1 = {0.0f, 0.0f, 0.0f, 0.0f};
#pragma unroll
    for (int kb = 0; kb < 2; ++kb) {
      f16x8 bh, bl;
#pragma unroll
      for (int j = 0; j < 8; ++j) {
        int I = kb * 8 + quad * 2 + (j >> 2);
        int idx = I * IBLK + (j & 3) * 64 + w * 16 + (li >> 2) * 4 + (li & 3);
        float v = Lb[idx];
        f16 hi = (f16)v;
        bh[j] = hi;
        bl[j] = (f16)(v - (float)hi);
      }
      acc0 = __builtin_amdgcn_mfma_f32_16x16x32_f16(ah[0][kb], bh, acc0, 0, 0, 0);
      acc0 = __builtin_amdgcn_mfma_f32_16x16x32_f16(ah[0][kb], bl, acc0, 0, 0, 0);
      acc0 = __builtin_amdgcn_mfma_f32_16x16x32_f16(al[0][kb], bh, acc0, 0, 0, 0);
      acc1 = __builtin_amdgcn_mfma_f32_16x16x32_f16(ah[1][kb], bh, acc1, 0, 0, 0);
      acc1 = __builtin_amdgcn_mfma_f32_16x16x32_f16(ah[1][kb], bl, acc1, 0, 0, 0);
      acc1 = __builtin_amdgcn_mfma_f32_16x16x32_f16(al[1][kb], bh, acc1, 0, 0, 0);
    }
#pragma unroll
    for (int r = 0; r < 4; ++r) {
      float d0 = acc0[r] + biasr[0][r];
      float d1 = acc1[r] + biasr[1][r];
      float y0 = d0 * __builtin_amdgcn_rcpf(1.0f + __expf(-d0));
      float y1 = d1 * __builtin_amdgcn_rcpf(1.0f + __expf(-d1));
      s1a[0][r] += y0; s2a[0][r] = fmaf(y0, y0, s2a[0][r]);
      s1a[1][r] += y1; s2a[1][r] = fmaf(y1, y1, s2a[1][r]);
    }
    __syncthreads();   // buf[cur] free for restage at p+2
  }

  // reduce over the 16 lanes of each quad (cols = times)
#pragma unroll
  for (int off = 8; off; off >>= 1) {
#pragma unroll
    for (int mt = 0; mt < 2; ++mt)
#pragma unroll
      for (int r = 0; r < 4; ++r) {
        s1a[mt][r] += __shfl_down(s1a[mt][r], off, 16);
        s2a[mt][r] += __shfl_down(s2a[mt][r], off, 16);
      }
  }

  if (li == 0) {
#pragma unroll
    for (int mt = 0; mt < 2; ++mt)
#pragma unroll
      for (int r = 0; r < 4; ++r) {
        int c = mt * 16 + quad * 4 + r;
        part[0][c][w] = s1a[mt][r];
        part[1][c][w] = s2a[mt][r];
      }
  }
  __syncthreads();
  if (tid < 64) {
    int c = tid >> 1, which = tid & 1;
    float v = part[which][c][0] + part[which][c][1] +
              part[which][c][2] + part[which][c][3];
    size_t o = (size_t)((b * CC) + g * 32 + c) * NSEG + seg;
    if (which == 0) S1[o] = v; else S2[o] = v;
  }
}

// ---------------- K2: tempo features + per-(b,c) 7x2 MHSA + out_proj --------
__global__ __launch_bounds__(256) void k2_attn(
    const float* __restrict__ S1, const float* __restrict__ S2,
    const float* __restrict__ ipw, const float* __restrict__ ipb,
    const float* __restrict__ opw, const float* __restrict__ opb,
    float* __restrict__ flat) {
  const float PSIN[TLEN] = {0.0f, 0.8414709848f, 0.9092974268f, 0.1411200081f,
                            -0.7568024953f, -0.9589242747f, -0.2794154982f};
  const float PCOS[TLEN] = {1.0f, 0.5403023059f, -0.4161468365f, -0.9899924966f,
                            -0.6536436209f, 0.2836621855f, 0.9601702867f};
  int idx = blockIdx.x * blockDim.x + threadIdx.x;
  if (idx >= BB * CC) return;
  int b = idx / CC, c = idx % CC;
  const float* s1 = S1 + (size_t)(b * CC + c) * NSEG;
  const float* s2 = S2 + (size_t)(b * CC + c) * NSEG;

  float yq[TLEN][2];
#pragma unroll
  for (int t = 0; t < TLEN; ++t) {
    float S1w = s1[t] + s1[t + 1];
    float S2w = s2[t] + s2[t + 1];
    float mean = S1w * (1.0f / 1024.0f);
    float var = (S2w - S1w * S1w * (1.0f / 1024.0f)) * (1.0f / 1023.0f);
    var = fminf(fmaxf(var, 1e-6f), 1e6f);
    float rms = sqrtf(S2w * (1.0f / 1024.0f));
    yq[t][0] = __logf(var) + PSIN[t];
    yq[t][1] = rms / mean + PCOS[t];
  }

  const float* W = ipw + c * 12;
  const float* Bp = ipb + c * 6;
  float q[TLEN][2], k[TLEN][2], v[TLEN][2];
#pragma unroll
  for (int t = 0; t < TLEN; ++t) {
#pragma unroll
    for (int f = 0; f < 6; ++f) {
      float val = W[f * 2 + 0] * yq[t][0] + W[f * 2 + 1] * yq[t][1] + Bp[f];
      if (f < 2) q[t][f] = val;
      else if (f < 4) k[t][f - 2] = val;
      else v[t][f - 4] = val;
    }
  }

  float o[TLEN][2];
#pragma unroll
  for (int h = 0; h < 2; ++h) {
#pragma unroll
    for (int t = 0; t < TLEN; ++t) {
      float sc[TLEN];
      float m = -1e30f;
#pragma unroll
      for (int s = 0; s < TLEN; ++s) {
        sc[s] = q[t][h] * k[s][h];
        m = fmaxf(m, sc[s]);
      }
      float sum = 0.0f, acc = 0.0f;
#pragma unroll
      for (int s = 0; s < TLEN; ++s) {
        float e = __expf(sc[s] - m);
        sum += e;
        acc += e * v[s][h];
      }
      o[t][h] = acc / sum;
    }
  }

  const float* Wo = opw + c * 4;
  const float* Bo = opb + c * 2;
  float* out = flat + (size_t)b * (CC * TLEN * 2) + c * (TLEN * 2);
#pragma unroll
  for (int t = 0; t < TLEN; ++t) {
    out[t * 2 + 0] = Wo[0] * o[t][0] + Wo[1] * o[t][1] + Bo[0];
    out[t * 2 + 1] = Wo[2] * o[t][0] + Wo[3] * o[t][1] + Bo[1];
  }
}

// ---------------- K3: classifier with renorm(last_w,0.5) + log_softmax ------
__global__ __launch_bounds__(256) void k3_cls(
    const float* __restrict__ flat, const float* __restrict__ lw,
    const float* __restrict__ lb, float* __restrict__ out) {
  const int FEAT = CC * TLEN * 2;  // 4032
  int b = blockIdx.x;
  int tid = threadIdx.x;
  const float* f = flat + (size_t)b * FEAT;
  float d[NCLASS] = {0, 0, 0, 0}, n2[NCLASS] = {0, 0, 0, 0};
  for (int j = tid; j < FEAT; j += 256) {
    float fv = f[j];
#pragma unroll
    for (int n = 0; n < NCLASS; ++n) {
      float w = lw[n * FEAT + j];
      d[n] = fmaf(fv, w, d[n]);
      n2[n] = fmaf(w, w, n2[n]);
    }
  }
  __shared__ float red[4][8];
  int lane = tid & 63, wave = tid >> 6;
#pragma unroll
  for (int n = 0; n < NCLASS; ++n) {
#pragma unroll
    for (int off = 32; off; off >>= 1) {
      d[n] += __shfl_down(d[n], off, 64);
      n2[n] += __shfl_down(n2[n], off, 64);
    }
  }
  if (lane == 0) {
#pragma unroll
    for (int n = 0; n < NCLASS; ++n) {
      red[wave][n] = d[n];
      red[wave][n + 4] = n2[n];
    }
  }
  __syncthreads();
  if (tid == 0) {
    float logit[NCLASS];
#pragma unroll
    for (int n = 0; n < NCLASS; ++n) {
      float dn = red[0][n] + red[1][n] + red[2][n] + red[3][n];
      float nn = red[0][n + 4] + red[1][n + 4] + red[2][n + 4] + red[3][n + 4];
      float norm = sqrtf(nn);
      float scale = fminf(1.0f, 0.5f / fmaxf(norm, 1e-7f));
      logit[n] = dn * scale + lb[n];
    }
    float m = fmaxf(fmaxf(logit[0], logit[1]), fmaxf(logit[2], logit[3]));
    float s = 0.0f;
#pragma unroll
    for (int n = 0; n < NCLASS; ++n) s += expf(logit[n] - m);
    float ls = logf(s);
#pragma unroll
    for (int n = 0; n < NCLASS; ++n) out[b * NCLASS + n] = logit[n] - m - ls;
  }
}

extern "C" void kernel_launch(void* const* d_in, const int* in_sizes, int n_in,
                              void* d_out, int out_size, void* d_ws, size_t ws_size,
                              hipStream_t stream) {
  const float* x     = (const float*)d_in[0];
  const float* cw    = (const float*)d_in[1];
  const float* cb    = (const float*)d_in[2];
  const float* gam   = (const float*)d_in[3];
  const float* bet   = (const float*)d_in[4];
  const float* mu    = (const float*)d_in[5];
  const float* var   = (const float*)d_in[6];
  const float* ipw   = (const float*)d_in[7];
  const float* ipb   = (const float*)d_in[8];
  const float* opw   = (const float*)d_in[9];
  const float* opb   = (const float*)d_in[10];
  const float* lw    = (const float*)d_in[11];
  const float* lb    = (const float*)d_in[12];
  float* out = (float*)d_out;

  float* ws = (float*)d_ws;
  f16* Wh = (f16*)(ws + WS_WF);
  f16* Wl = Wh + CC * NCHAN;
  float* biasf = ws + WS_BIAS;
  float* S1    = ws + WS_S1;
  float* S2    = ws + WS_S2;
  float* flat  = ws + WS_FLAT;

  k0_fold<<<CC, 64, 0, stream>>>(cw, cb, gam, bet, mu, var, Wh, Wl, biasf);
  k1_conv<<<BB * NBANDS * NSEG, 256, 0, stream>>>(x, Wh, Wl, biasf, S1, S2);
  k2_attn<<<(BB * CC + 255) / 256, 256, 0, stream>>>(S1, S2, ipw, ipb, opw, opb, flat);
  k3_cls<<<BB, 256, 0, stream>>>(flat, lw, lb, out);
}